// Round 1
// baseline (57.456 us; speedup 1.0000x reference)
//
#include <hip/hip_runtime.h>
#include <math.h>

#define B 16
#define N 1024
#define D 512
#define K 32
#define EPSF 1e-12f

// workspace layout (float offsets)
#define WS_SA   0          // B*N*K = 524288
#define WS_T    524288     // B*N*K
#define WS_ENT  1048576    // B*N
#define WS_AS   1064960    // B*K
#define WS_MSP  1065472    // B
#define WS_ENTP 1065488    // B
#define WS_CT   1065504    // K*D
#define WS_PART 1081888    // S*B*K*D

#define OFF_DIST 262144
#define OFF_ENT  262656

// Kernel 1: per 8 rows: normalize, logits = xn@W + b (masked), softmax,
// entropy, store sa and t = sa*inv_norm.
__global__ __launch_bounds__(256) void k1_rows(const float* __restrict__ x,
    const float* __restrict__ mask, const float* __restrict__ W,
    const float* __restrict__ bias, float* __restrict__ ws)
{
    __shared__ float xs[8 * 512];        // 16KB
    __shared__ float pm[8 * 8 * 32];     // 8KB
    __shared__ float inv_s[8];
    const int bid = blockIdx.x;          // 0..2047
    const int b = bid >> 7;              // /128
    const int n0 = (bid & 127) * 8;
    const int t = threadIdx.x;

    // load 8 rows of x (float4, coalesced)
    {
        const float4* xg = (const float4*)(x + (size_t)(b * N + n0) * D);
        float4* xs4 = (float4*)xs;
        #pragma unroll
        for (int j = 0; j < 4; ++j) xs4[t + j * 256] = xg[t + j * 256];
    }
    __syncthreads();

    // per-row sumsq: 32 lanes per row
    {
        const float4* xs4 = (const float4*)xs;
        int r = t >> 5, l = t & 31;
        float ss = 0.f;
        #pragma unroll
        for (int j = 0; j < 4; ++j) {
            float4 v = xs4[r * 128 + l + j * 32];
            ss += v.x * v.x + v.y * v.y + v.z * v.z + v.w * v.w;
        }
        #pragma unroll
        for (int mm = 16; mm; mm >>= 1) ss += __shfl_xor(ss, mm);
        if (l == 0) inv_s[r] = 1.f / fmaxf(sqrtf(ss), EPSF);
    }
    __syncthreads();

    // dot products: thread = (k = t&31, seg = t>>5), 64 d per seg, 8 rows
    {
        int k = t & 31, seg = t >> 5;
        float acc[8] = {0.f, 0.f, 0.f, 0.f, 0.f, 0.f, 0.f, 0.f};
        const float2* xs2 = (const float2*)xs;
        const float* Wp = W + k;
        int dbase = seg * 64;
        #pragma unroll 4
        for (int dd = 0; dd < 64; dd += 2) {
            int d = dbase + dd;
            float w0 = Wp[(size_t)d * 32];
            float w1 = Wp[(size_t)(d + 1) * 32];
            int d2 = d >> 1;
            #pragma unroll
            for (int r = 0; r < 8; ++r) {
                float2 xv = xs2[r * 256 + d2];
                acc[r] = fmaf(xv.x, w0, acc[r]);
                acc[r] = fmaf(xv.y, w1, acc[r]);
            }
        }
        #pragma unroll
        for (int r = 0; r < 8; ++r) pm[(r * 8 + seg) * 32 + k] = acc[r];
    }
    __syncthreads();

    // logits -> masked softmax -> sa, t, entropy
    {
        int row = t >> 5, k = t & 31;
        float s = 0.f;
        #pragma unroll
        for (int g = 0; g < 8; ++g) s += pm[(row * 8 + g) * 32 + k];
        int n = n0 + row;
        float m = mask[b * N + n];
        float inv = inv_s[row];
        float logit = (s * inv + bias[k]) * m;
        float mx = logit;
        #pragma unroll
        for (int mm = 16; mm; mm >>= 1) mx = fmaxf(mx, __shfl_xor(mx, mm));
        float e = __expf(logit - mx);
        float sum = e;
        #pragma unroll
        for (int mm = 16; mm; mm >>= 1) sum += __shfl_xor(sum, mm);
        float p = e / sum;
        float sa = p * m;
        size_t o = (size_t)(b * N + n) * K + k;
        ws[WS_SA + o] = sa;
        ws[WS_T + o] = sa * inv;
        float ek = sa > 0.f ? -sa * __log2f(sa) : 0.f;
        #pragma unroll
        for (int mm = 16; mm; mm >>= 1) ek += __shfl_xor(ek, mm);
        if (k == 0) ws[WS_ENT + b * N + n] = ek;
    }
}

// Kernel 2: per-b reductions: assign_sum, assign_dist (log_softmax),
// mask/entropy partials; block 0 also transposes centroids into ws.
__global__ __launch_bounds__(256) void k2_reduce(const float* __restrict__ mask,
    const float* __restrict__ cent, float* __restrict__ ws, float* __restrict__ out)
{
    __shared__ float pm[8 * 32];
    __shared__ float red[8];
    const int b = blockIdx.x;
    const int t = threadIdx.x;

    // assign_sum over n
    {
        int k = t & 31, g = t >> 5;
        float a = 0.f;
        const float* sap = ws + WS_SA + ((size_t)b * N + g * 128) * K + k;
        for (int n = 0; n < 128; ++n) a += sap[n * K];
        pm[g * 32 + k] = a;
    }
    __syncthreads();
    if (t < 32) {
        float a = 0.f;
        #pragma unroll
        for (int g = 0; g < 8; ++g) a += pm[g * 32 + t];
        ws[WS_AS + b * K + t] = a;
        float mx = a;
        #pragma unroll
        for (int mm = 16; mm; mm >>= 1) mx = fmaxf(mx, __shfl_xor(mx, mm));
        float e = __expf(a - mx), s = e;
        #pragma unroll
        for (int mm = 16; mm; mm >>= 1) s += __shfl_xor(s, mm);
        out[OFF_DIST + b * K + t] = a - mx - __logf(s);
    }

    // mask & entropy partial sums for this b
    {
        float msum = 0.f, esum = 0.f;
        #pragma unroll
        for (int j = 0; j < 4; ++j) {
            int idx = t + j * 256;
            msum += mask[b * N + idx];
            esum += ws[WS_ENT + b * N + idx];
        }
        #pragma unroll
        for (int mm = 32; mm; mm >>= 1) {
            msum += __shfl_xor(msum, mm);
            esum += __shfl_xor(esum, mm);
        }
        int lane = t & 63, w = t >> 6;
        if (lane == 0) { red[w] = msum; red[4 + w] = esum; }
        __syncthreads();
        if (t == 0) {
            float mt = 0.f, et = 0.f;
            #pragma unroll
            for (int i = 0; i < 4; ++i) { mt += red[i]; et += red[4 + i]; }
            ws[WS_MSP + b] = mt;
            ws[WS_ENTP + b] = et;
        }
    }

    // centroid transpose (once)
    if (b == 0) {
        for (int i = t; i < D * K; i += 256) {
            int d = i >> 5, k = i & 31;
            ws[WS_CT + k * D + d] = cent[i];
        }
    }
}

// Kernel 3: vlad partial GEMM: part[s][b][k][d] = sum_{n in split s} x[n,d]*t[n,k]
__global__ __launch_bounds__(256) void k3_vlad(const float* __restrict__ x,
    const float* __restrict__ tws, float* __restrict__ part, int S, int NS)
{
    __shared__ float xs[32 * 128];  // 16KB
    __shared__ float ts[32 * 32];   // 4KB
    const int t = threadIdx.x;
    int bid = blockIdx.x;
    int b = bid / (4 * S);
    int rem = bid % (4 * S);
    int dt = rem / S;
    int s = rem % S;
    int n0 = s * NS;
    int dg = t & 31, kg = t >> 5;
    float acc[4][4];
    #pragma unroll
    for (int j = 0; j < 4; ++j)
        #pragma unroll
        for (int i = 0; i < 4; ++i) acc[j][i] = 0.f;

    const float4* xs4 = (const float4*)xs;
    const float4* ts4 = (const float4*)ts;
    int nchunks = NS >> 5;
    for (int c = 0; c < nchunks; ++c) {
        int nb = n0 + c * 32;
        {
            float4* xsw = (float4*)xs;
            const float4* xg = (const float4*)x;
            #pragma unroll
            for (int j = 0; j < 4; ++j) {
                int idx = t + j * 256;
                int row = idx >> 5, col = idx & 31;
                xsw[idx] = xg[(size_t)(b * N + nb + row) * 128 + dt * 32 + col];
            }
            float4* tsw = (float4*)ts;
            const float4* tg = (const float4*)tws;
            int row = t >> 3, col = t & 7;
            tsw[t] = tg[(size_t)(b * N + nb + row) * 8 + col];
        }
        __syncthreads();
        #pragma unroll 4
        for (int r = 0; r < 32; ++r) {
            float4 xv = xs4[r * 32 + dg];
            float4 tv = ts4[r * 8 + kg];
            float xvd[4] = {xv.x, xv.y, xv.z, xv.w};
            float tvk[4] = {tv.x, tv.y, tv.z, tv.w};
            #pragma unroll
            for (int j = 0; j < 4; ++j)
                #pragma unroll
                for (int i = 0; i < 4; ++i)
                    acc[j][i] = fmaf(tvk[j], xvd[i], acc[j][i]);
        }
        __syncthreads();
    }
    #pragma unroll
    for (int j = 0; j < 4; ++j) {
        int k = kg * 4 + j;
        float4 v = make_float4(acc[j][0], acc[j][1], acc[j][2], acc[j][3]);
        ((float4*)part)[(((size_t)(s * B + b) * K + k) * D >> 2) + dg] = v;
    }
}

// Kernel 4: sum partials, subtract centroid term, intra-normalize over D,
// write transposed output (B,K,D); block 0 finalizes entropy scalar.
__global__ __launch_bounds__(256) void k4_final(const float* __restrict__ ws,
    const float* __restrict__ part, float* __restrict__ out, int S)
{
    __shared__ float red[4];
    __shared__ float scs;
    int bid = blockIdx.x;
    int b = bid >> 5, k = bid & 31;
    int t = threadIdx.x;
    float as = ws[WS_AS + b * K + k];
    float v0 = 0.f, v1 = 0.f;
    for (int s = 0; s < S; ++s) {
        const float* pp = part + ((size_t)(s * B + b) * K + k) * D;
        v0 += pp[t];
        v1 += pp[t + 256];
    }
    v0 -= ws[WS_CT + k * D + t] * as;
    v1 -= ws[WS_CT + k * D + t + 256] * as;
    float ss = v0 * v0 + v1 * v1;
    #pragma unroll
    for (int mm = 32; mm; mm >>= 1) ss += __shfl_xor(ss, mm);
    if ((t & 63) == 0) red[t >> 6] = ss;
    __syncthreads();
    if (t == 0) {
        float tot = red[0] + red[1] + red[2] + red[3];
        scs = 1.f / fmaxf(sqrtf(tot), EPSF);
    }
    __syncthreads();
    float sc = scs;
    out[(size_t)(b * K + k) * D + t] = v0 * sc;
    out[(size_t)(b * K + k) * D + t + 256] = v1 * sc;
    if (bid == 0 && t == 0) {
        float ms = 0.f, es = 0.f;
        #pragma unroll
        for (int i = 0; i < B; ++i) { ms += ws[WS_MSP + i]; es += ws[WS_ENTP + i]; }
        out[OFF_ENT] = es / ms;
    }
}

extern "C" void kernel_launch(void* const* d_in, const int* in_sizes, int n_in,
                              void* d_out, int out_size, void* d_ws, size_t ws_size,
                              hipStream_t stream)
{
    const float* x    = (const float*)d_in[0];
    const float* mask = (const float*)d_in[1];
    const float* W    = (const float*)d_in[2];
    const float* bias = (const float*)d_in[3];
    const float* cent = (const float*)d_in[4];
    float* out = (float*)d_out;
    float* ws  = (float*)d_ws;

    int S = 8;
    while (S > 1 && ws_size < (size_t)(WS_PART + (size_t)S * B * K * D) * sizeof(float))
        S >>= 1;
    int NS = N / S;

    k1_rows<<<dim3(B * N / 8), dim3(256), 0, stream>>>(x, mask, W, bias, ws);
    k2_reduce<<<dim3(B), dim3(256), 0, stream>>>(mask, cent, ws, out);
    k3_vlad<<<dim3(B * 4 * S), dim3(256), 0, stream>>>(x, ws + WS_T, ws + WS_PART, S, NS);
    k4_final<<<dim3(B * K), dim3(256), 0, stream>>>(ws, ws + WS_PART, out, S);
}

// Round 2
// 47.435 us; speedup vs baseline: 1.2113x; 1.2113x over previous
//
#include <hip/hip_runtime.h>
#include <math.h>

#define B 16
#define N 1024
#define D 512
#define K 32
#define EPSF 1e-12f

// ws layout (float offsets)
#define WS_T_F    0        // t bf16 [B*N][K] : 524288 ushort = 262144 floats
#define WS_WT_F   262144   // WT bf16 [K][D]  : 16384 ushort = 8192 floats
#define WS_ASP_F  270336   // assign partials [1024 blocks][K] = 32768
#define WS_ENTP_F 303104   // 1024
#define WS_MSKP_F 304128   // 1024
#define WS_AS_F   305152   // B*K = 512
#define WS_CT_F   305664   // CT f32 [K][D] = 16384
#define WS_PART_F 322048   // parts [S=8][B][K][D] = 2097152

#define OFF_DIST 262144
#define OFF_ENT  262656

typedef __attribute__((ext_vector_type(8))) short s16x8;
typedef __attribute__((ext_vector_type(4))) short s16x4;
typedef __attribute__((ext_vector_type(4))) float f32x4;

__device__ __forceinline__ ushort f2b(float f) {
    unsigned u = __builtin_bit_cast(unsigned, f);
    u += 0x7fffu + ((u >> 16) & 1u);   // RTNE
    return (ushort)(u >> 16);
}

// k0: block 0: W[d][k] f32 -> WT[k][d] bf16 ; block 1: cent[d][k] -> CT[k][d] f32
__global__ __launch_bounds__(256) void k0_prep(const float* __restrict__ Wf,
    const float* __restrict__ cent, float* __restrict__ ws)
{
    const int t = threadIdx.x;
    const int kk = t >> 3, dseg = (t & 7) * 64;
    if (blockIdx.x == 0) {
        ushort* wt = (ushort*)(ws + WS_WT_F);
        #pragma unroll
        for (int d8 = 0; d8 < 8; ++d8) {
            s16x8 v;
            #pragma unroll
            for (int e = 0; e < 8; ++e)
                v[e] = f2b(Wf[(dseg + d8 * 8 + e) * 32 + kk]);
            *(s16x8*)(wt + kk * 512 + dseg + d8 * 8) = v;
        }
    } else {
        float* ct = ws + WS_CT_F;
        #pragma unroll
        for (int d4 = 0; d4 < 16; ++d4) {
            float4 v;
            v.x = cent[(dseg + d4 * 4 + 0) * 32 + kk];
            v.y = cent[(dseg + d4 * 4 + 1) * 32 + kk];
            v.z = cent[(dseg + d4 * 4 + 2) * 32 + kk];
            v.w = cent[(dseg + d4 * 4 + 3) * 32 + kk];
            *(float4*)(ct + kk * 512 + dseg + d4 * 4) = v;
        }
    }
}

// k1: 1 wave / 16 rows. logits^T = WT(A) @ x^T(B) via MFMA, fused softmax.
// Writes t bf16 [n][k], block partials: assign_sum[K], entropy, mask-sum.
__global__ __launch_bounds__(64) void k1_rows(const float* __restrict__ x,
    const float* __restrict__ mask, const float* __restrict__ bias,
    float* __restrict__ ws)
{
    __shared__ ushort xs[16 * 128];   // 4KB, swizzled bf16 [16 n][128 d-chunk]
    __shared__ float inv_s[16];
    const int bid = blockIdx.x;       // 0..1023
    const int b = bid >> 6;
    const int n0 = (bid & 63) << 4;
    const int l = threadIdx.x;        // 0..63
    const int g = l >> 4, lo = l & 15;
    const ushort* wt = (const ushort*)(ws + WS_WT_F);

    float ssq[8] = {0.f, 0.f, 0.f, 0.f, 0.f, 0.f, 0.f, 0.f};
    f32x4 acc[2] = {{0.f, 0.f, 0.f, 0.f}, {0.f, 0.f, 0.f, 0.f}};

    const float4* xg = (const float4*)(x + (size_t)(b * N + n0) * D);
    for (int c = 0; c < 4; ++c) {
        float4 fv[8];
        #pragma unroll
        for (int j = 0; j < 8; ++j) {
            int idx = l + 64 * j;
            int r = idx >> 5, c4 = idx & 31;
            fv[j] = xg[r * 128 + c * 32 + c4];
        }
        #pragma unroll
        for (int j = 0; j < 8; ++j)
            ssq[j] += fv[j].x * fv[j].x + fv[j].y * fv[j].y
                    + fv[j].z * fv[j].z + fv[j].w * fv[j].w;
        #pragma unroll
        for (int j = 0; j < 8; ++j) {
            int idx = l + 64 * j;
            int r = idx >> 5, c4 = idx & 31;
            unsigned bo = (unsigned)(c4 * 8) ^ (unsigned)((r & 7) << 4);
            s16x4 sv = { (short)f2b(fv[j].x), (short)f2b(fv[j].y),
                         (short)f2b(fv[j].z), (short)f2b(fv[j].w) };
            *(s16x4*)&xs[r * 128 + (bo >> 1)] = sv;
        }
        __syncthreads();
        #pragma unroll
        for (int ks = 0; ks < 4; ++ks) {
            unsigned bo = (unsigned)(ks * 64 + g * 16) ^ (unsigned)((lo & 7) << 4);
            s16x8 bfrag = *(const s16x8*)&xs[lo * 128 + (bo >> 1)];
            int dglob = c * 128 + ks * 32 + g * 8;
            s16x8 a0 = *(const s16x8*)(wt + (size_t)lo * 512 + dglob);
            s16x8 a1 = *(const s16x8*)(wt + (size_t)(16 + lo) * 512 + dglob);
            acc[0] = __builtin_amdgcn_mfma_f32_16x16x32_bf16(a0, bfrag, acc[0], 0, 0, 0);
            acc[1] = __builtin_amdgcn_mfma_f32_16x16x32_bf16(a1, bfrag, acc[1], 0, 0, 0);
        }
        __syncthreads();
    }

    // row sumsq -> inv_s (rows (l>>5)+2j, reduce over 32 lanes sharing l>>5)
    #pragma unroll
    for (int j = 0; j < 8; ++j) {
        #pragma unroll
        for (int m = 16; m; m >>= 1) ssq[j] += __shfl_xor(ssq[j], m);
    }
    if ((l & 31) == 0) {
        #pragma unroll
        for (int j = 0; j < 8; ++j)
            inv_s[(l >> 5) + 2 * j] = 1.f / fmaxf(sqrtf(ssq[j]), EPSF);
    }
    __syncthreads();

    // epilogue: lane -> n = n0+lo, k = kt*16 + g*4 + r
    const float inv = inv_s[lo];
    const float mv = mask[b * N + n0 + lo];
    float lg[2][4];
    #pragma unroll
    for (int kt = 0; kt < 2; ++kt)
        #pragma unroll
        for (int r = 0; r < 4; ++r)
            lg[kt][r] = (acc[kt][r] * inv + bias[kt * 16 + g * 4 + r]) * mv;
    float mx = lg[0][0];
    #pragma unroll
    for (int kt = 0; kt < 2; ++kt)
        #pragma unroll
        for (int r = 0; r < 4; ++r) mx = fmaxf(mx, lg[kt][r]);
    mx = fmaxf(mx, __shfl_xor(mx, 16));
    mx = fmaxf(mx, __shfl_xor(mx, 32));
    float e[2][4], sum = 0.f;
    #pragma unroll
    for (int kt = 0; kt < 2; ++kt)
        #pragma unroll
        for (int r = 0; r < 4; ++r) { e[kt][r] = __expf(lg[kt][r] - mx); sum += e[kt][r]; }
    sum += __shfl_xor(sum, 16);
    sum += __shfl_xor(sum, 32);
    const float rs = mv / sum;
    float sa[2][4], ent = 0.f;
    #pragma unroll
    for (int kt = 0; kt < 2; ++kt)
        #pragma unroll
        for (int r = 0; r < 4; ++r) {
            sa[kt][r] = e[kt][r] * rs;
            ent += sa[kt][r] > 0.f ? -sa[kt][r] * __log2f(sa[kt][r]) : 0.f;
        }
    // t bf16 write: [n][k], 8B per kt
    ushort* tg = (ushort*)(ws + WS_T_F);
    #pragma unroll
    for (int kt = 0; kt < 2; ++kt) {
        s16x4 tv = { (short)f2b(sa[kt][0] * inv), (short)f2b(sa[kt][1] * inv),
                     (short)f2b(sa[kt][2] * inv), (short)f2b(sa[kt][3] * inv) };
        *(s16x4*)(tg + (size_t)(b * N + n0 + lo) * 32 + kt * 16 + g * 4) = tv;
    }
    // block partials
    #pragma unroll
    for (int m = 32; m; m >>= 1) ent += __shfl_xor(ent, m);
    if (l == 0) ws[WS_ENTP_F + bid] = ent;
    float mp = mv;
    #pragma unroll
    for (int m = 8; m; m >>= 1) mp += __shfl_xor(mp, m);
    if (l == 0) ws[WS_MSKP_F + bid] = mp;
    #pragma unroll
    for (int kt = 0; kt < 2; ++kt)
        #pragma unroll
        for (int r = 0; r < 4; ++r) {
            float av = sa[kt][r];
            #pragma unroll
            for (int m = 8; m; m >>= 1) av += __shfl_xor(av, m);
            if (lo == 0) ws[WS_ASP_F + bid * 32 + kt * 16 + g * 4 + r] = av;
        }
}

// k2: blocks 0..15: assign_sum + log_softmax; block 16: entropy scalar
__global__ __launch_bounds__(64) void k2_reduce(float* __restrict__ ws,
    float* __restrict__ out)
{
    const int b = blockIdx.x;
    const int l = threadIdx.x;
    if (b < 16) {
        int k = l & 31, h = l >> 5;
        float a = 0.f;
        for (int i = h; i < 64; i += 2)
            a += ws[WS_ASP_F + (b * 64 + i) * 32 + k];
        a += __shfl_xor(a, 32);
        if (l < 32) ws[WS_AS_F + b * 32 + k] = a;
        float mx = a;
        #pragma unroll
        for (int m = 16; m; m >>= 1) mx = fmaxf(mx, __shfl_xor(mx, m));
        float e = __expf(a - mx), s = e;
        #pragma unroll
        for (int m = 16; m; m >>= 1) s += __shfl_xor(s, m);
        if (l < 32) out[OFF_DIST + b * 32 + k] = a - mx - logf(s);
    } else {
        float es = 0.f, ms = 0.f;
        for (int i = l; i < 1024; i += 64) {
            es += ws[WS_ENTP_F + i];
            ms += ws[WS_MSKP_F + i];
        }
        #pragma unroll
        for (int m = 32; m; m >>= 1) { es += __shfl_xor(es, m); ms += __shfl_xor(ms, m); }
        if (l == 0) out[OFF_ENT] = es / ms;
    }
}

// k3: parts[s][b][k][d] = sum_{n in split} t[n][k] * x[n][d]  (MFMA, no LDS)
__global__ __launch_bounds__(256) void k3_vlad(const float* __restrict__ x,
    const float* __restrict__ ws, float* __restrict__ parts)
{
    const int bid = blockIdx.x;          // 512 = b(16) * s(8) * dh(4)
    const int b = bid >> 5;
    const int s = (bid >> 2) & 7;
    const int dh = bid & 3;
    const int w = threadIdx.x >> 6;
    const int l = threadIdx.x & 63;
    const int g = l >> 4, lo = l & 15;
    const int d0 = dh * 128 + w * 32;
    const ushort* tg = (const ushort*)(ws + WS_T_F);

    f32x4 acc[2][2] = {{{0.f,0.f,0.f,0.f},{0.f,0.f,0.f,0.f}},
                       {{0.f,0.f,0.f,0.f},{0.f,0.f,0.f,0.f}}};
    for (int ks = 0; ks < 4; ++ks) {
        int nb = s * 128 + ks * 32 + g * 8;
        s16x8 av[2];
        #pragma unroll
        for (int kt = 0; kt < 2; ++kt)
            #pragma unroll
            for (int j = 0; j < 8; ++j)
                av[kt][j] = (short)tg[(size_t)(b * N + nb + j) * 32 + kt * 16 + lo];
        s16x8 bv[2];
        #pragma unroll
        for (int dt = 0; dt < 2; ++dt)
            #pragma unroll
            for (int j = 0; j < 8; ++j)
                bv[dt][j] = (short)f2b(x[(size_t)(b * N + nb + j) * 512 + d0 + dt * 16 + lo]);
        #pragma unroll
        for (int kt = 0; kt < 2; ++kt)
            #pragma unroll
            for (int dt = 0; dt < 2; ++dt)
                acc[kt][dt] = __builtin_amdgcn_mfma_f32_16x16x32_bf16(av[kt], bv[dt], acc[kt][dt], 0, 0, 0);
    }
    #pragma unroll
    for (int kt = 0; kt < 2; ++kt)
        #pragma unroll
        for (int dt = 0; dt < 2; ++dt)
            #pragma unroll
            for (int r = 0; r < 4; ++r) {
                int k = kt * 16 + g * 4 + r;
                int d = d0 + dt * 16 + lo;
                parts[((size_t)(s * 16 + b) * 32 + k) * 512 + d] = acc[kt][dt][r];
            }
}

// k4: sum partials, subtract centroid term, intra-normalize over D, write (B,K,D)
__global__ __launch_bounds__(256) void k4_final(const float* __restrict__ ws,
    float* __restrict__ out)
{
    __shared__ float red[4];
    __shared__ float scs;
    const int bid = blockIdx.x;
    const int b = bid >> 5, k = bid & 31;
    const int t = threadIdx.x;
    const float* parts = ws + WS_PART_F;
    const float as = ws[WS_AS_F + b * 32 + k];
    float v0 = 0.f, v1 = 0.f;
    #pragma unroll
    for (int s = 0; s < 8; ++s) {
        const float* pp = parts + ((size_t)(s * 16 + b) * 32 + k) * 512;
        v0 += pp[t];
        v1 += pp[t + 256];
    }
    v0 -= ws[WS_CT_F + k * 512 + t] * as;
    v1 -= ws[WS_CT_F + k * 512 + t + 256] * as;
    float ss = v0 * v0 + v1 * v1;
    #pragma unroll
    for (int m = 32; m; m >>= 1) ss += __shfl_xor(ss, m);
    if ((t & 63) == 0) red[t >> 6] = ss;
    __syncthreads();
    if (t == 0) {
        float tot = red[0] + red[1] + red[2] + red[3];
        scs = 1.f / fmaxf(sqrtf(tot), EPSF);
    }
    __syncthreads();
    const float sc = scs;
    out[(size_t)(b * 32 + k) * 512 + t] = v0 * sc;
    out[(size_t)(b * 32 + k) * 512 + t + 256] = v1 * sc;
}

extern "C" void kernel_launch(void* const* d_in, const int* in_sizes, int n_in,
                              void* d_out, int out_size, void* d_ws, size_t ws_size,
                              hipStream_t stream)
{
    const float* x    = (const float*)d_in[0];
    const float* mask = (const float*)d_in[1];
    const float* W    = (const float*)d_in[2];
    const float* bias = (const float*)d_in[3];
    const float* cent = (const float*)d_in[4];
    float* out = (float*)d_out;
    float* ws  = (float*)d_ws;

    k0_prep<<<dim3(2), dim3(256), 0, stream>>>(W, cent, ws);
    k1_rows<<<dim3(1024), dim3(64), 0, stream>>>(x, mask, bias, ws);
    k2_reduce<<<dim3(17), dim3(64), 0, stream>>>(ws, out);
    k3_vlad<<<dim3(512), dim3(256), 0, stream>>>(x, ws, ws + WS_PART_F);
    k4_final<<<dim3(512), dim3(256), 0, stream>>>(ws, out);
}

// Round 3
// 33.994 us; speedup vs baseline: 1.6902x; 1.3954x over previous
//
#include <hip/hip_runtime.h>
#include <math.h>

#define B 16
#define N 1024
#define D 512
#define K 32
#define EPSF 1e-12f

// ws float offsets
#define WS_TT_F   0         // tT bf16 [B][K][N] = 524288 ushort = 262144 f
#define WS_ASP_F  262144    // assign partials [1024][32]
#define WS_ENTP_F 294912    // [1024]
#define WS_MSKP_F 295936    // [1024]
#define WS_PART_F 296960    // parts [8][16][32][512] f32

#define OFF_DIST 262144
#define OFF_ENT  262656

typedef __attribute__((ext_vector_type(8))) short s16x8;
typedef __attribute__((ext_vector_type(4))) short s16x4;
typedef __attribute__((ext_vector_type(4))) float f32x4;

__device__ __forceinline__ ushort f2b(float f) {
    unsigned u = __builtin_bit_cast(unsigned, f);
    u += 0x7fffu + ((u >> 16) & 1u);   // RTNE
    return (ushort)(u >> 16);
}

// kA: 512 blocks (b,s32) x 256 thr. Waves: rw = row-half (16 rows each),
// dw = d-half (256 d each). Inline W->bf16 LDS convert; MFMA logits;
// cross-wave acc combine; fused masked softmax; writes tT bf16 + partials.
__global__ __launch_bounds__(256) void kA(const float* __restrict__ x,
    const float* __restrict__ mask, const float* __restrict__ Wf,
    const float* __restrict__ bias, float* __restrict__ ws)
{
    __shared__ ushort wtl[32 * 512];      // 32KB swizzled WT bf16
    __shared__ ushort xs[4 * 16 * 128];   // 16KB per-wave x tiles
    __shared__ float4 accsh[2 * 128];     // 4KB dw=1 partial acc
    __shared__ float ssqsh[2 * 16];
    __shared__ float invsh[2 * 16];
    const int bid = blockIdx.x;
    const int b = bid >> 5;
    const int s = bid & 31;
    const int tid = threadIdx.x;
    const int w = tid >> 6;
    const int rw = w & 1, dw = w >> 1;
    const int l = tid & 63;
    const int g = l >> 4, lo = l & 15;
    const int n0 = s * 32 + rw * 16;
    const int p = bid * 2 + rw;

    // inline W[d][k] f32 -> wtl[k][d] bf16 (swizzled), all threads
    {
        const float4* Wg = (const float4*)Wf;
        #pragma unroll
        for (int i = 0; i < 16; ++i) {
            int f4 = tid + i * 256;
            float4 v = Wg[f4];
            int d = f4 >> 3, k4 = (f4 & 7) << 2;
            float vv[4] = {v.x, v.y, v.z, v.w};
            #pragma unroll
            for (int j = 0; j < 4; ++j) {
                int k = k4 + j;
                wtl[(k * 512 + d) ^ ((k & 7) << 3)] = f2b(vv[j]);
            }
        }
    }

    ushort* xw = xs + w * 2048;
    float ssq[8] = {0.f, 0.f, 0.f, 0.f, 0.f, 0.f, 0.f, 0.f};
    f32x4 acc[2] = {{0.f, 0.f, 0.f, 0.f}, {0.f, 0.f, 0.f, 0.f}};
    const float4* xg = (const float4*)(x + (size_t)(b * N + n0) * D);
    __syncthreads();   // wtl ready

    #pragma unroll
    for (int cc = 0; cc < 2; ++cc) {
        const int c = dw * 2 + cc;
        float4 fv[8];
        #pragma unroll
        for (int j = 0; j < 8; ++j) {
            int idx = l + 64 * j;
            fv[j] = xg[(idx >> 5) * 128 + c * 32 + (idx & 31)];
        }
        #pragma unroll
        for (int j = 0; j < 8; ++j)
            ssq[j] += fv[j].x * fv[j].x + fv[j].y * fv[j].y
                    + fv[j].z * fv[j].z + fv[j].w * fv[j].w;
        #pragma unroll
        for (int j = 0; j < 8; ++j) {
            int idx = l + 64 * j;
            int r = idx >> 5, c4 = idx & 31;
            unsigned bo = (unsigned)(c4 * 8) ^ (unsigned)((r & 7) << 4);
            s16x4 sv = { (short)f2b(fv[j].x), (short)f2b(fv[j].y),
                         (short)f2b(fv[j].z), (short)f2b(fv[j].w) };
            *(s16x4*)&xw[r * 128 + (bo >> 1)] = sv;
        }
        __syncthreads();
        #pragma unroll
        for (int ks = 0; ks < 4; ++ks) {
            unsigned bo = (unsigned)(ks * 64 + g * 16) ^ (unsigned)((lo & 7) << 4);
            s16x8 bfrag = *(const s16x8*)&xw[lo * 128 + (bo >> 1)];
            int dglob = c * 128 + ks * 32 + g * 8;
            s16x8 a0 = *(const s16x8*)&wtl[(lo * 512 + dglob) ^ ((lo & 7) << 3)];
            s16x8 a1 = *(const s16x8*)&wtl[((16 + lo) * 512 + dglob) ^ ((lo & 7) << 3)];
            acc[0] = __builtin_amdgcn_mfma_f32_16x16x32_bf16(a0, bfrag, acc[0], 0, 0, 0);
            acc[1] = __builtin_amdgcn_mfma_f32_16x16x32_bf16(a1, bfrag, acc[1], 0, 0, 0);
        }
        __syncthreads();
    }

    // per-row sumsq (this wave's d-half): rows (l>>5)+2j, 32-lane butterfly
    #pragma unroll
    for (int j = 0; j < 8; ++j) {
        #pragma unroll
        for (int m = 16; m; m >>= 1) ssq[j] += __shfl_xor(ssq[j], m);
    }
    if (dw == 1) {
        if ((l & 31) == 0) {
            #pragma unroll
            for (int j = 0; j < 8; ++j)
                ssqsh[rw * 16 + (l >> 5) + 2 * j] = ssq[j];
        }
        accsh[rw * 128 + l * 2 + 0] = *(float4*)&acc[0];
        accsh[rw * 128 + l * 2 + 1] = *(float4*)&acc[1];
    }
    __syncthreads();
    if (dw == 0) {
        float4 o0 = accsh[rw * 128 + l * 2 + 0];
        float4 o1 = accsh[rw * 128 + l * 2 + 1];
        acc[0][0] += o0.x; acc[0][1] += o0.y; acc[0][2] += o0.z; acc[0][3] += o0.w;
        acc[1][0] += o1.x; acc[1][1] += o1.y; acc[1][2] += o1.z; acc[1][3] += o1.w;
        if ((l & 31) == 0) {
            #pragma unroll
            for (int j = 0; j < 8; ++j) {
                int r = (l >> 5) + 2 * j;
                invsh[rw * 16 + r] = 1.f / fmaxf(sqrtf(ssq[j] + ssqsh[rw * 16 + r]), EPSF);
            }
        }
    }
    __syncthreads();
    float sa[2][4];
    if (dw == 0) {
        const float inv = invsh[rw * 16 + lo];
        const float mv = mask[b * N + n0 + lo];
        float lg[2][4];
        #pragma unroll
        for (int kt = 0; kt < 2; ++kt)
            #pragma unroll
            for (int r = 0; r < 4; ++r)
                lg[kt][r] = (acc[kt][r] * inv + bias[kt * 16 + g * 4 + r]) * mv;
        float mx = lg[0][0];
        #pragma unroll
        for (int kt = 0; kt < 2; ++kt)
            #pragma unroll
            for (int r = 0; r < 4; ++r) mx = fmaxf(mx, lg[kt][r]);
        mx = fmaxf(mx, __shfl_xor(mx, 16));
        mx = fmaxf(mx, __shfl_xor(mx, 32));
        float e[2][4], sum = 0.f;
        #pragma unroll
        for (int kt = 0; kt < 2; ++kt)
            #pragma unroll
            for (int r = 0; r < 4; ++r) { e[kt][r] = __expf(lg[kt][r] - mx); sum += e[kt][r]; }
        sum += __shfl_xor(sum, 16);
        sum += __shfl_xor(sum, 32);
        const float rs = mv / sum;
        float ent = 0.f;
        #pragma unroll
        for (int kt = 0; kt < 2; ++kt)
            #pragma unroll
            for (int r = 0; r < 4; ++r) {
                sa[kt][r] = e[kt][r] * rs;
                ent += sa[kt][r] > 0.f ? -sa[kt][r] * __log2f(sa[kt][r]) : 0.f;
            }
        #pragma unroll
        for (int m = 32; m; m >>= 1) ent += __shfl_xor(ent, m);
        if (l == 0) ws[WS_ENTP_F + p] = ent;
        float mp = mv;
        #pragma unroll
        for (int m = 8; m; m >>= 1) mp += __shfl_xor(mp, m);
        if (l == 0) ws[WS_MSKP_F + p] = mp;
        #pragma unroll
        for (int kt = 0; kt < 2; ++kt)
            #pragma unroll
            for (int r = 0; r < 4; ++r) {
                float av = sa[kt][r];
                #pragma unroll
                for (int m = 8; m; m >>= 1) av += __shfl_xor(av, m);
                if (lo == 0) ws[WS_ASP_F + p * 32 + kt * 16 + g * 4 + r] = av;
            }
        // t^T into LDS: tls[k][n-local], k = kt*16+g*4+r, n-local = lo
        #pragma unroll
        for (int kt = 0; kt < 2; ++kt)
            #pragma unroll
            for (int r = 0; r < 4; ++r)
                xw[(kt * 16 + g * 4 + r) * 16 + lo] = f2b(sa[kt][r] * inv);
    }
    __syncthreads();
    if (dw == 0) {
        ushort* tTg = (ushort*)ws;   // WS_TT_F = 0
        s16x8 tv = *(const s16x8*)&xw[l * 8];
        *(s16x8*)(tTg + (size_t)(b * 32 + (l >> 1)) * 1024 + n0 + (l & 1) * 8) = tv;
    }
}

// kB: parts[s][b][k][d] = sum_n t[n][k]*x[n][d]. A-frags: 16B loads from tT.
__global__ __launch_bounds__(256) void kB(const float* __restrict__ x,
    const float* __restrict__ ws, float* __restrict__ parts)
{
    const int bid = blockIdx.x;          // 512 = b(16) * s(8) * dh(4)
    const int b = bid >> 5;
    const int s = (bid >> 2) & 7;
    const int dh = bid & 3;
    const int w = threadIdx.x >> 6;
    const int l = threadIdx.x & 63;
    const int g = l >> 4, lo = l & 15;
    const int d0 = dh * 128 + w * 32;
    const ushort* tT = (const ushort*)ws;

    f32x4 acc[2][2] = {{{0.f,0.f,0.f,0.f},{0.f,0.f,0.f,0.f}},
                       {{0.f,0.f,0.f,0.f},{0.f,0.f,0.f,0.f}}};
    for (int ks = 0; ks < 4; ++ks) {
        int nb = s * 128 + ks * 32 + g * 8;
        s16x8 av[2];
        av[0] = *(const s16x8*)(tT + (size_t)(b * 32 + lo) * 1024 + nb);
        av[1] = *(const s16x8*)(tT + (size_t)(b * 32 + 16 + lo) * 1024 + nb);
        s16x8 bv[2];
        #pragma unroll
        for (int dt = 0; dt < 2; ++dt)
            #pragma unroll
            for (int j = 0; j < 8; ++j)
                bv[dt][j] = (short)f2b(x[(size_t)(b * N + nb + j) * 512 + d0 + dt * 16 + lo]);
        #pragma unroll
        for (int kt = 0; kt < 2; ++kt)
            #pragma unroll
            for (int dt = 0; dt < 2; ++dt)
                acc[kt][dt] = __builtin_amdgcn_mfma_f32_16x16x32_bf16(av[kt], bv[dt], acc[kt][dt], 0, 0, 0);
    }
    #pragma unroll
    for (int kt = 0; kt < 2; ++kt)
        #pragma unroll
        for (int dt = 0; dt < 2; ++dt)
            #pragma unroll
            for (int r = 0; r < 4; ++r) {
                int k = kt * 16 + g * 4 + r;
                int d = d0 + dt * 16 + lo;
                parts[((size_t)(s * 16 + b) * 32 + k) * 512 + d] = acc[kt][dt][r];
            }
}

// kC: assign_sum from partials, log_softmax dist (k==0 blocks), entropy
// (block 0), vlad finalize: sum parts - cent*as, intra-norm, write (B,K,D).
__global__ __launch_bounds__(256) void kC(const float* __restrict__ cent,
    const float* __restrict__ ws, float* __restrict__ out)
{
    __shared__ float pm[256];
    __shared__ float asL[32];
    __shared__ float red[4];
    __shared__ float scs;
    const int bid = blockIdx.x;
    const int b = bid >> 5, k = bid & 31;
    const int t = threadIdx.x;
    {
        int kk = t & 31, i = t >> 5;
        float a = 0.f;
        #pragma unroll
        for (int ii = 0; ii < 8; ++ii)
            a += ws[WS_ASP_F + (size_t)(b * 64 + ii * 8 + i) * 32 + kk];
        pm[t] = a;
    }
    __syncthreads();
    if (t < 32) {
        float a = 0.f;
        #pragma unroll
        for (int i = 0; i < 8; ++i) a += pm[i * 32 + t];
        asL[t] = a;
    }
    __syncthreads();
    if (k == 0 && t < 32) {
        float a = asL[t];
        float mx = a;
        #pragma unroll
        for (int m = 16; m; m >>= 1) mx = fmaxf(mx, __shfl_xor(mx, m));
        float e = __expf(a - mx), ssum = e;
        #pragma unroll
        for (int m = 16; m; m >>= 1) ssum += __shfl_xor(ssum, m);
        out[OFF_DIST + b * 32 + t] = a - mx - logf(ssum);
    }
    if (bid == 0 && (t >> 6) == 1) {
        int l = t & 63;
        float es = 0.f, ms = 0.f;
        for (int i = l; i < 1024; i += 64) {
            es += ws[WS_ENTP_F + i];
            ms += ws[WS_MSKP_F + i];
        }
        #pragma unroll
        for (int m = 32; m; m >>= 1) { es += __shfl_xor(es, m); ms += __shfl_xor(ms, m); }
        if (l == 0) out[OFF_ENT] = es / ms;
    }
    const float as = asL[k];
    float v0 = 0.f, v1 = 0.f;
    #pragma unroll
    for (int s = 0; s < 8; ++s) {
        const float* pp = ws + WS_PART_F + ((size_t)(s * 16 + b) * 32 + k) * 512;
        v0 += pp[t];
        v1 += pp[t + 256];
    }
    v0 -= cent[t * 32 + k] * as;
    v1 -= cent[(t + 256) * 32 + k] * as;
    float ss = v0 * v0 + v1 * v1;
    #pragma unroll
    for (int m = 32; m; m >>= 1) ss += __shfl_xor(ss, m);
    if ((t & 63) == 0) red[t >> 6] = ss;
    __syncthreads();
    if (t == 0) scs = 1.f / fmaxf(sqrtf(red[0] + red[1] + red[2] + red[3]), EPSF);
    __syncthreads();
    out[(size_t)(b * 32 + k) * 512 + t] = v0 * scs;
    out[(size_t)(b * 32 + k) * 512 + t + 256] = v1 * scs;
}

extern "C" void kernel_launch(void* const* d_in, const int* in_sizes, int n_in,
                              void* d_out, int out_size, void* d_ws, size_t ws_size,
                              hipStream_t stream)
{
    const float* x    = (const float*)d_in[0];
    const float* mask = (const float*)d_in[1];
    const float* W    = (const float*)d_in[2];
    const float* bias = (const float*)d_in[3];
    const float* cent = (const float*)d_in[4];
    float* out = (float*)d_out;
    float* ws  = (float*)d_ws;

    kA<<<dim3(512), dim3(256), 0, stream>>>(x, mask, W, bias, ws);
    kB<<<dim3(512), dim3(256), 0, stream>>>(x, ws, ws + WS_PART_F);
    kC<<<dim3(512), dim3(256), 0, stream>>>(cent, ws, out);
}